// Round 1
// baseline (563.978 us; speedup 1.0000x reference)
//
#include <hip/hip_runtime.h>
#include <hip/hip_fp16.h>

typedef _Float16 half8 __attribute__((ext_vector_type(8)));
typedef _Float16 half4v __attribute__((ext_vector_type(4)));
typedef float floatx4 __attribute__((ext_vector_type(4)));

// ---------------- async global->LDS (16B per lane) ----------------
__device__ __forceinline__ void load_lds16(const void* g, void* l) {
    __builtin_amdgcn_global_load_lds(
        (const __attribute__((address_space(1))) void*)g,
        (__attribute__((address_space(3))) void*)l,
        16, 0, 0);
}

// stage a 128x32 fp16 tile (row-major, k-contiguous) into LDS.
// gsrc points at the tile's first row; ld is the global leading dim (elements).
__device__ __forceinline__ void stage_tile(const _Float16* gsrc, long ld, int k0,
                                           _Float16* lds) {
    const int t = threadIdx.x;  // 256 threads
#pragma unroll
    for (int i = 0; i < 2; ++i) {
        const int idx8 = (i * 256 + t) * 8;   // element index in [128][32] tile
        const int row  = idx8 >> 5;
        const int col  = idx8 & 31;
        load_lds16(gsrc + (long)row * ld + (k0 + col), lds + idx8);
    }
}

// ---------------- 128x128 gemm_bt core: C[m,n] = sum_k A[m,k]*B[n,k] ----------------
// 256 threads = 4 waves in a 2x2 wave grid; each wave owns a 64x64 subtile
// = 4x4 fragments of 16x16, MFMA 16x16x32 f16, fp32 accum.
__device__ __forceinline__ void gemm_core(const _Float16* Atile, long lda,
                                          const _Float16* Btile, long ldb,
                                          int K, floatx4 acc[4][4],
                                          _Float16* As, _Float16* Bs) {
    const int lane = threadIdx.x & 63;
    const int w    = threadIdx.x >> 6;
    const int wr   = w >> 1, wc = w & 1;
    const int rsel = lane & 15, gsel = lane >> 4;

    for (int k0 = 0; k0 < K; k0 += 32) {
        stage_tile(Atile, lda, k0, As);
        stage_tile(Btile, ldb, k0, Bs);
        __syncthreads();  // drains vmcnt -> tiles in LDS
        half8 af[4], bfr[4];
#pragma unroll
        for (int m = 0; m < 4; ++m)
            af[m] = *(const half8*)&As[(wr * 64 + m * 16 + rsel) * 32 + gsel * 8];
#pragma unroll
        for (int n = 0; n < 4; ++n)
            bfr[n] = *(const half8*)&Bs[(wc * 64 + n * 16 + rsel) * 32 + gsel * 8];
#pragma unroll
        for (int m = 0; m < 4; ++m)
#pragma unroll
            for (int n = 0; n < 4; ++n)
                acc[m][n] = __builtin_amdgcn_mfma_f32_16x16x32_f16(af[m], bfr[n],
                                                                   acc[m][n], 0, 0, 0);
        __syncthreads();  // protect LDS reuse
    }
}

__device__ __forceinline__ void zero_acc(floatx4 acc[4][4]) {
    const floatx4 z = {0.f, 0.f, 0.f, 0.f};
#pragma unroll
    for (int m = 0; m < 4; ++m)
#pragma unroll
        for (int n = 0; n < 4; ++n) acc[m][n] = z;
}

// ---------------- kernels ----------------

// concat embeddings [B,S,256|256|512] fp32 -> X fp16 [16384][1024]
__global__ __launch_bounds__(256) void build_x_kernel(const float* e1, const float* e2,
                                                      const float* e3, _Float16* X) {
    long i = ((long)blockIdx.x * 256 + threadIdx.x) * 4;  // < 16384*1024
    int m = (int)(i >> 10);
    int c = (int)(i & 1023);
    const float* src;
    if (c < 256)      src = e1 + (long)m * 256 + c;
    else if (c < 512) src = e2 + (long)m * 256 + (c - 256);
    else              src = e3 + (long)m * 512 + (c - 512);
    float4 f = *(const float4*)src;
    half4v h;
    h[0] = (_Float16)f.x; h[1] = (_Float16)f.y;
    h[2] = (_Float16)f.z; h[3] = (_Float16)f.w;
    *(half4v*)&X[i] = h;
}

// Wq,Wk,Wv,Wf fp32 [1024][1024] -> Wh fp16 [4][1024][1024]
__global__ __launch_bounds__(256) void conv_w_kernel(const float* Wq, const float* Wk,
                                                     const float* Wv, const float* Wf,
                                                     _Float16* dst) {
    long i = ((long)blockIdx.x * 256 + threadIdx.x) * 4;  // < 4*1048576
    int which = (int)(i >> 20);
    long off = i & 1048575;
    const float* w = which == 0 ? Wq : which == 1 ? Wk : which == 2 ? Wv : Wf;
    float4 f = *(const float4*)(w + off);
    half4v h;
    h[0] = (_Float16)f.x; h[1] = (_Float16)f.y;
    h[2] = (_Float16)f.z; h[3] = (_Float16)f.w;
    *(half4v*)&dst[i] = h;
}

// QKV projection: z=0 -> q, z=1 -> k (row-major [16384][1024]),
// z=2 -> v written TRANSPOSED as vT [1024][16384] (so PV is gemm_bt form).
__global__ __launch_bounds__(256) void qkv_kernel(const _Float16* X, const _Float16* W,
                                                  const float* bq, const float* bk,
                                                  const float* bv, _Float16* q,
                                                  _Float16* k, _Float16* vT) {
    __shared__ alignas(16) _Float16 As[4096];
    __shared__ alignas(16) _Float16 Bs[4096];
    const int m0 = blockIdx.x * 128;
    const int n0 = blockIdx.y * 128;
    const int z  = blockIdx.z;
    const _Float16* A = X + (long)m0 * 1024;
    const _Float16* B = W + (long)z * 1048576 + (long)n0 * 1024;
    floatx4 acc[4][4];
    zero_acc(acc);
    gemm_core(A, 1024, B, 1024, 1024, acc, As, Bs);

    const float* bias = (z == 0) ? bq : (z == 1) ? bk : bv;
    const int lane = threadIdx.x & 63;
    const int w = threadIdx.x >> 6;
    const int wr = w >> 1, wc = w & 1;
#pragma unroll
    for (int m = 0; m < 4; ++m) {
#pragma unroll
        for (int n = 0; n < 4; ++n) {
            const int r = wr * 64 + m * 16 + (lane >> 4) * 4;  // + j
            const int c = wc * 64 + n * 16 + (lane & 15);
            const float bb = bias[n0 + c];
            if (z == 2) {
                half4v vv;
#pragma unroll
                for (int j = 0; j < 4; ++j) vv[j] = (_Float16)(acc[m][n][j] + bb);
                *(half4v*)&vT[(long)(n0 + c) * 16384 + (m0 + r)] = vv;
            } else {
                _Float16* dst = (z == 0) ? q : k;
#pragma unroll
                for (int j = 0; j < 4; ++j)
                    dst[(long)(m0 + r + j) * 1024 + (n0 + c)] =
                        (_Float16)(acc[m][n][j] + bb);
            }
        }
    }
}

// scores[b] = q[b] @ k[b]^T  (fp32 out, chunk-local batch index bz)
__global__ __launch_bounds__(256) void scores_kernel(const _Float16* qh,
                                                     const _Float16* kh, float* scores,
                                                     int b0) {
    __shared__ alignas(16) _Float16 As[4096];
    __shared__ alignas(16) _Float16 Bs[4096];
    const int m0 = blockIdx.x * 128;
    const int n0 = blockIdx.y * 128;
    const int bz = blockIdx.z;
    const int batch = b0 + bz;
    const _Float16* A = qh + ((long)batch * 2048 + m0) * 1024;
    const _Float16* B = kh + ((long)batch * 2048 + n0) * 1024;
    float* C = scores + (long)bz * 2048 * 2048;
    floatx4 acc[4][4];
    zero_acc(acc);
    gemm_core(A, 1024, B, 1024, 1024, acc, As, Bs);

    const int lane = threadIdx.x & 63;
    const int w = threadIdx.x >> 6;
    const int wr = w >> 1, wc = w & 1;
#pragma unroll
    for (int m = 0; m < 4; ++m) {
#pragma unroll
        for (int n = 0; n < 4; ++n) {
            const int r = wr * 64 + m * 16 + (lane >> 4) * 4;
            const int c = wc * 64 + n * 16 + (lane & 15);
#pragma unroll
            for (int j = 0; j < 4; ++j)
                C[(long)(m0 + r + j) * 2048 + (n0 + c)] = acc[m][n][j];
        }
    }
}

// row softmax over 2048 fp32 scores -> fp16 probs. one block per row.
__global__ __launch_bounds__(256) void softmax_kernel(const float* scores,
                                                      _Float16* probs, int b0) {
    const int row = blockIdx.x;  // 0..2047
    const int bz  = blockIdx.y;  // chunk-local batch
    const float* s = scores + ((long)bz * 2048 + row) * 2048;
    _Float16* p = probs + ((long)(b0 + bz) * 2048 + row) * 2048;
    const int t = threadIdx.x;

    float4 x0 = ((const float4*)s)[t * 2];
    float4 x1 = ((const float4*)s)[t * 2 + 1];
    float v[8] = {x0.x, x0.y, x0.z, x0.w, x1.x, x1.y, x1.z, x1.w};

    float mx = v[0];
#pragma unroll
    for (int j = 1; j < 8; ++j) mx = fmaxf(mx, v[j]);
#pragma unroll
    for (int d = 1; d < 64; d <<= 1) mx = fmaxf(mx, __shfl_xor(mx, d));
    __shared__ float smax[4];
    __shared__ float ssum[4];
    if ((t & 63) == 0) smax[t >> 6] = mx;
    __syncthreads();
    mx = fmaxf(fmaxf(smax[0], smax[1]), fmaxf(smax[2], smax[3]));

    float e[8];
    float sum = 0.f;
#pragma unroll
    for (int j = 0; j < 8; ++j) {
        e[j] = __expf(v[j] - mx);
        sum += e[j];
    }
#pragma unroll
    for (int d = 1; d < 64; d <<= 1) sum += __shfl_xor(sum, d);
    if ((t & 63) == 0) ssum[t >> 6] = sum;
    __syncthreads();
    sum = ssum[0] + ssum[1] + ssum[2] + ssum[3];
    const float inv = 1.0f / sum;

    half8 o;
#pragma unroll
    for (int j = 0; j < 8; ++j) o[j] = (_Float16)(e[j] * inv);
    *(half8*)&p[t * 8] = o;
}

// weighted[b] = probs[b] @ v[b]  via vT (gemm_bt form). fp16 out [16384][1024].
__global__ __launch_bounds__(256) void pv_kernel(const _Float16* probs,
                                                 const _Float16* vT, _Float16* wt) {
    __shared__ alignas(16) _Float16 As[4096];
    __shared__ alignas(16) _Float16 Bs[4096];
    const int m0 = blockIdx.x * 128;
    const int n0 = blockIdx.y * 128;
    const int batch = blockIdx.z;
    const _Float16* A = probs + ((long)batch * 2048 + m0) * 2048;
    const _Float16* B = vT + (long)n0 * 16384 + (long)batch * 2048;
    floatx4 acc[4][4];
    zero_acc(acc);
    gemm_core(A, 2048, B, 16384, 2048, acc, As, Bs);

    const int lane = threadIdx.x & 63;
    const int w = threadIdx.x >> 6;
    const int wr = w >> 1, wc = w & 1;
#pragma unroll
    for (int m = 0; m < 4; ++m) {
#pragma unroll
        for (int n = 0; n < 4; ++n) {
            const int r = wr * 64 + m * 16 + (lane >> 4) * 4;
            const int c = wc * 64 + n * 16 + (lane & 15);
#pragma unroll
            for (int j = 0; j < 4; ++j)
                wt[(long)(batch * 2048 + m0 + r + j) * 1024 + (n0 + c)] =
                    (_Float16)acc[m][n][j];
        }
    }
}

// out = leakyrelu(weighted @ Wf^T + bf), fp32 out.
__global__ __launch_bounds__(256) void out_kernel(const _Float16* wt, const _Float16* Wf,
                                                  const float* bf_, float* out) {
    __shared__ alignas(16) _Float16 As[4096];
    __shared__ alignas(16) _Float16 Bs[4096];
    const int m0 = blockIdx.x * 128;
    const int n0 = blockIdx.y * 128;
    const _Float16* A = wt + (long)m0 * 1024;
    const _Float16* B = Wf + (long)n0 * 1024;
    floatx4 acc[4][4];
    zero_acc(acc);
    gemm_core(A, 1024, B, 1024, 1024, acc, As, Bs);

    const int lane = threadIdx.x & 63;
    const int w = threadIdx.x >> 6;
    const int wr = w >> 1, wc = w & 1;
#pragma unroll
    for (int m = 0; m < 4; ++m) {
#pragma unroll
        for (int n = 0; n < 4; ++n) {
            const int r = wr * 64 + m * 16 + (lane >> 4) * 4;
            const int c = wc * 64 + n * 16 + (lane & 15);
            const float bb = bf_[n0 + c];
#pragma unroll
            for (int j = 0; j < 4; ++j) {
                float y = acc[m][n][j] + bb;
                y = (y >= 0.f) ? y : 0.2f * y;
                out[(long)(m0 + r + j) * 1024 + (n0 + c)] = y;
            }
        }
    }
}

// ---------------- launcher ----------------
extern "C" void kernel_launch(void* const* d_in, const int* in_sizes, int n_in,
                              void* d_out, int out_size, void* d_ws, size_t ws_size,
                              hipStream_t stream) {
    const float* e1 = (const float*)d_in[0];
    const float* e2 = (const float*)d_in[1];
    const float* e3 = (const float*)d_in[2];
    const float* Wq = (const float*)d_in[3];
    const float* bq = (const float*)d_in[4];
    const float* Wk = (const float*)d_in[5];
    const float* bk = (const float*)d_in[6];
    const float* Wv = (const float*)d_in[7];
    const float* bv = (const float*)d_in[8];
    const float* Wf = (const float*)d_in[9];
    const float* bf_ = (const float*)d_in[10];
    float* out = (float*)d_out;

    char* ws = (char*)d_ws;
    const size_t MB = 1024 * 1024;
    _Float16* Xh    = (_Float16*)(ws + 0);        // 32 MiB
    _Float16* Wh    = (_Float16*)(ws + 32 * MB);  // 8 MiB [4][1024][1024]
    _Float16* qh    = (_Float16*)(ws + 40 * MB);  // 32 MiB
    _Float16* kh    = (_Float16*)(ws + 72 * MB);  // 32 MiB
    _Float16* vT    = (_Float16*)(ws + 104 * MB); // 32 MiB [1024][16384]
    _Float16* wt    = (_Float16*)(ws + 136 * MB); // 32 MiB
    _Float16* probs = (_Float16*)(ws + 168 * MB); // 64 MiB [8][2048][2048]
    float* scores   = (float*)(ws + 232 * MB);    // NB * 16 MiB scratch

    long nb_max = ((long)ws_size - 232 * (long)MB) / (16 * (long)MB);
    int NB = (int)(nb_max < 1 ? 1 : (nb_max > 8 ? 8 : nb_max));

    build_x_kernel<<<16384, 256, 0, stream>>>(e1, e2, e3, Xh);
    conv_w_kernel<<<4096, 256, 0, stream>>>(Wq, Wk, Wv, Wf, Wh);
    qkv_kernel<<<dim3(128, 8, 3), 256, 0, stream>>>(Xh, Wh, bq, bk, bv, qh, kh, vT);
    for (int b0 = 0; b0 < 8; b0 += NB) {
        int nb = 8 - b0 < NB ? 8 - b0 : NB;
        scores_kernel<<<dim3(16, 16, nb), 256, 0, stream>>>(qh, kh, scores, b0);
        softmax_kernel<<<dim3(2048, nb), 256, 0, stream>>>(scores, probs, b0);
    }
    pv_kernel<<<dim3(16, 8, 8), 256, 0, stream>>>(probs, vT, wt);
    out_kernel<<<dim3(128, 8), 256, 0, stream>>>(wt, Wh + 3 * 1048576, bf_, out);
}

// Round 2
// 493.412 us; speedup vs baseline: 1.1430x; 1.1430x over previous
//
#include <hip/hip_runtime.h>
#include <hip/hip_fp16.h>

typedef _Float16 half8 __attribute__((ext_vector_type(8)));
typedef _Float16 half4v __attribute__((ext_vector_type(4)));
typedef float floatx4 __attribute__((ext_vector_type(4)));

// ---------------- async global->LDS (16B per lane) ----------------
__device__ __forceinline__ void load_lds16(const void* g, void* l) {
    __builtin_amdgcn_global_load_lds(
        (const __attribute__((address_space(1))) void*)g,
        (__attribute__((address_space(3))) void*)l,
        16, 0, 0);
}

// Stage a 128x64 fp16 tile into LDS with XOR-swizzled 16B slots.
// LDS layout: chunk c (16B) at linear offset c*16; logical (row, slot):
// row = c>>3, stored slot = c&7, holds global slot (c&7)^(row&7).
// (swizzle is an involution; readers XOR the same way)
__device__ __forceinline__ void stage128x64(const _Float16* g, long ld, _Float16* lds) {
    const int t = threadIdx.x;  // 256 threads, 4 chunks each
#pragma unroll
    for (int i = 0; i < 4; ++i) {
        const int c    = i * 256 + t;          // 0..1023
        const int row  = c >> 3;               // 0..127
        const int slot = (c & 7) ^ (row & 7);  // pre-swizzled global source
        load_lds16(g + (long)row * ld + slot * 8, lds + c * 8);
    }
}

// ---------------- 128x128 gemm_bt core: C[m,n] = sum_k A[m,k]*B[n,k] ----------------
// BK=64, double-buffered LDS (2 x (A 16KB + B 16KB) = 64KB), one barrier per
// K-tile, stage(t+1) issued BEFORE tile t's MFMAs, vmcnt(0) drained AFTER.
// 256 threads = 4 waves (2x2), each wave owns 64x64 = 4x4 frags of 16x16x32.
__device__ __forceinline__ void gemm_core(const _Float16* A, long lda,
                                          const _Float16* B, long ldb,
                                          int K, floatx4 acc[4][4],
                                          _Float16* As, _Float16* Bs) {
    const int lane = threadIdx.x & 63;
    const int w    = threadIdx.x >> 6;
    const int wr   = w >> 1, wc = w & 1;
    const int rsel = lane & 15, gsel = lane >> 4;
    const int sw   = rsel & 7;
    const int s0   = (gsel ^ sw) * 8;   // k-half 0 swizzled slot offset (elements)
    const int s1   = s0 ^ 32;           // k-half 1 (slot ^ 4)
    const int nt   = K >> 6;

    // prologue: stage tile 0 into buffer 0
    stage128x64(A, lda, As);
    stage128x64(B, ldb, Bs);
    asm volatile("s_waitcnt vmcnt(0)" ::: "memory");
    __builtin_amdgcn_s_barrier();
    __builtin_amdgcn_sched_barrier(0);

    for (int t = 0; t < nt; ++t) {
        _Float16* Ab = As + (t & 1) * 8192;
        _Float16* Bb = Bs + (t & 1) * 8192;
        // issue next tile's stage first: latency hides under this tile's MFMAs
        if (t + 1 < nt) {
            stage128x64(A + (t + 1) * 64, lda, As + ((t + 1) & 1) * 8192);
            stage128x64(B + (t + 1) * 64, ldb, Bs + ((t + 1) & 1) * 8192);
        }
        __builtin_amdgcn_sched_barrier(0);  // keep stage issue ahead of compute

        half8 af[4], bfr[4];
        // ---- k-half 0 (k = 0..31 of this tile) ----
#pragma unroll
        for (int m = 0; m < 4; ++m)
            af[m] = *(const half8*)&Ab[(wr * 64 + m * 16 + rsel) * 64 + s0];
#pragma unroll
        for (int n = 0; n < 4; ++n)
            bfr[n] = *(const half8*)&Bb[(wc * 64 + n * 16 + rsel) * 64 + s0];
        __builtin_amdgcn_s_setprio(1);
#pragma unroll
        for (int m = 0; m < 4; ++m)
#pragma unroll
            for (int n = 0; n < 4; ++n)
                acc[m][n] = __builtin_amdgcn_mfma_f32_16x16x32_f16(af[m], bfr[n],
                                                                   acc[m][n], 0, 0, 0);
        __builtin_amdgcn_s_setprio(0);
        // ---- k-half 1 (k = 32..63) ----
#pragma unroll
        for (int m = 0; m < 4; ++m)
            af[m] = *(const half8*)&Ab[(wr * 64 + m * 16 + rsel) * 64 + s1];
#pragma unroll
        for (int n = 0; n < 4; ++n)
            bfr[n] = *(const half8*)&Bb[(wc * 64 + n * 16 + rsel) * 64 + s1];
        __builtin_amdgcn_s_setprio(1);
#pragma unroll
        for (int m = 0; m < 4; ++m)
#pragma unroll
            for (int n = 0; n < 4; ++n)
                acc[m][n] = __builtin_amdgcn_mfma_f32_16x16x32_f16(af[m], bfr[n],
                                                                   acc[m][n], 0, 0, 0);
        __builtin_amdgcn_s_setprio(0);

        // drain next tile's loads (issued ~64 MFMAs ago) and flip buffers
        asm volatile("s_waitcnt vmcnt(0)" ::: "memory");
        __builtin_amdgcn_s_barrier();
        __builtin_amdgcn_sched_barrier(0);
    }
}

__device__ __forceinline__ void zero_acc(floatx4 acc[4][4]) {
    const floatx4 z = {0.f, 0.f, 0.f, 0.f};
#pragma unroll
    for (int m = 0; m < 4; ++m)
#pragma unroll
        for (int n = 0; n < 4; ++n) acc[m][n] = z;
}

// ---------------- kernels ----------------

// concat embeddings [B,S,256|256|512] fp32 -> X fp16 [16384][1024]
__global__ __launch_bounds__(256) void build_x_kernel(const float* e1, const float* e2,
                                                      const float* e3, _Float16* X) {
    long i = ((long)blockIdx.x * 256 + threadIdx.x) * 4;  // < 16384*1024
    int m = (int)(i >> 10);
    int c = (int)(i & 1023);
    const float* src;
    if (c < 256)      src = e1 + (long)m * 256 + c;
    else if (c < 512) src = e2 + (long)m * 256 + (c - 256);
    else              src = e3 + (long)m * 512 + (c - 512);
    float4 f = *(const float4*)src;
    half4v h;
    h[0] = (_Float16)f.x; h[1] = (_Float16)f.y;
    h[2] = (_Float16)f.z; h[3] = (_Float16)f.w;
    *(half4v*)&X[i] = h;
}

// Wq,Wk,Wv,Wf fp32 [1024][1024] -> Wh fp16 [4][1024][1024]
__global__ __launch_bounds__(256) void conv_w_kernel(const float* Wq, const float* Wk,
                                                     const float* Wv, const float* Wf,
                                                     _Float16* dst) {
    long i = ((long)blockIdx.x * 256 + threadIdx.x) * 4;  // < 4*1048576
    int which = (int)(i >> 20);
    long off = i & 1048575;
    const float* w = which == 0 ? Wq : which == 1 ? Wk : which == 2 ? Wv : Wf;
    float4 f = *(const float4*)(w + off);
    half4v h;
    h[0] = (_Float16)f.x; h[1] = (_Float16)f.y;
    h[2] = (_Float16)f.z; h[3] = (_Float16)f.w;
    *(half4v*)&dst[i] = h;
}

// QKV projection: z=0 -> q, z=1 -> k (row-major [16384][1024]),
// z=2 -> v written TRANSPOSED as vT [1024][16384] (so PV is gemm_bt form).
__global__ __launch_bounds__(256, 2) void qkv_kernel(const _Float16* X, const _Float16* W,
                                                     const float* bq, const float* bk,
                                                     const float* bv, _Float16* q,
                                                     _Float16* k, _Float16* vT) {
    __shared__ alignas(16) _Float16 As[16384];
    __shared__ alignas(16) _Float16 Bs[16384];
    const int m0 = blockIdx.x * 128;
    const int n0 = blockIdx.y * 128;
    const int z  = blockIdx.z;
    const _Float16* A = X + (long)m0 * 1024;
    const _Float16* B = W + (long)z * 1048576 + (long)n0 * 1024;
    floatx4 acc[4][4];
    zero_acc(acc);
    gemm_core(A, 1024, B, 1024, 1024, acc, As, Bs);

    const float* bias = (z == 0) ? bq : (z == 1) ? bk : bv;
    const int lane = threadIdx.x & 63;
    const int w = threadIdx.x >> 6;
    const int wr = w >> 1, wc = w & 1;
#pragma unroll
    for (int m = 0; m < 4; ++m) {
#pragma unroll
        for (int n = 0; n < 4; ++n) {
            const int r = wr * 64 + m * 16 + (lane >> 4) * 4;  // + j
            const int c = wc * 64 + n * 16 + (lane & 15);
            const float bb = bias[n0 + c];
            if (z == 2) {
                half4v vv;
#pragma unroll
                for (int j = 0; j < 4; ++j) vv[j] = (_Float16)(acc[m][n][j] + bb);
                *(half4v*)&vT[(long)(n0 + c) * 16384 + (m0 + r)] = vv;
            } else {
                _Float16* dst = (z == 0) ? q : k;
#pragma unroll
                for (int j = 0; j < 4; ++j)
                    dst[(long)(m0 + r + j) * 1024 + (n0 + c)] =
                        (_Float16)(acc[m][n][j] + bb);
            }
        }
    }
}

// scores[b] = q[b] @ k[b]^T  (fp32 out, chunk-local batch index bz)
__global__ __launch_bounds__(256, 2) void scores_kernel(const _Float16* qh,
                                                        const _Float16* kh, float* scores,
                                                        int b0) {
    __shared__ alignas(16) _Float16 As[16384];
    __shared__ alignas(16) _Float16 Bs[16384];
    const int m0 = blockIdx.x * 128;
    const int n0 = blockIdx.y * 128;
    const int bz = blockIdx.z;
    const int batch = b0 + bz;
    const _Float16* A = qh + ((long)batch * 2048 + m0) * 1024;
    const _Float16* B = kh + ((long)batch * 2048 + n0) * 1024;
    float* C = scores + (long)bz * 2048 * 2048;
    floatx4 acc[4][4];
    zero_acc(acc);
    gemm_core(A, 1024, B, 1024, 1024, acc, As, Bs);

    const int lane = threadIdx.x & 63;
    const int w = threadIdx.x >> 6;
    const int wr = w >> 1, wc = w & 1;
#pragma unroll
    for (int m = 0; m < 4; ++m) {
#pragma unroll
        for (int n = 0; n < 4; ++n) {
            const int r = wr * 64 + m * 16 + (lane >> 4) * 4;
            const int c = wc * 64 + n * 16 + (lane & 15);
#pragma unroll
            for (int j = 0; j < 4; ++j)
                C[(long)(m0 + r + j) * 2048 + (n0 + c)] = acc[m][n][j];
        }
    }
}

// row softmax over 2048 fp32 scores -> fp16 probs. one block per row.
__global__ __launch_bounds__(256) void softmax_kernel(const float* scores,
                                                      _Float16* probs, int b0) {
    const int row = blockIdx.x;  // 0..2047
    const int bz  = blockIdx.y;  // chunk-local batch
    const float* s = scores + ((long)bz * 2048 + row) * 2048;
    _Float16* p = probs + ((long)(b0 + bz) * 2048 + row) * 2048;
    const int t = threadIdx.x;

    float4 x0 = ((const float4*)s)[t * 2];
    float4 x1 = ((const float4*)s)[t * 2 + 1];
    float v[8] = {x0.x, x0.y, x0.z, x0.w, x1.x, x1.y, x1.z, x1.w};

    float mx = v[0];
#pragma unroll
    for (int j = 1; j < 8; ++j) mx = fmaxf(mx, v[j]);
#pragma unroll
    for (int d = 1; d < 64; d <<= 1) mx = fmaxf(mx, __shfl_xor(mx, d));
    __shared__ float smax[4];
    __shared__ float ssum[4];
    if ((t & 63) == 0) smax[t >> 6] = mx;
    __syncthreads();
    mx = fmaxf(fmaxf(smax[0], smax[1]), fmaxf(smax[2], smax[3]));

    float e[8];
    float sum = 0.f;
#pragma unroll
    for (int j = 0; j < 8; ++j) {
        e[j] = __expf(v[j] - mx);
        sum += e[j];
    }
#pragma unroll
    for (int d = 1; d < 64; d <<= 1) sum += __shfl_xor(sum, d);
    if ((t & 63) == 0) ssum[t >> 6] = sum;
    __syncthreads();
    sum = ssum[0] + ssum[1] + ssum[2] + ssum[3];
    const float inv = 1.0f / sum;

    half8 o;
#pragma unroll
    for (int j = 0; j < 8; ++j) o[j] = (_Float16)(e[j] * inv);
    *(half8*)&p[t * 8] = o;
}

// weighted[b] = probs[b] @ v[b]  via vT (gemm_bt form). fp16 out [16384][1024].
__global__ __launch_bounds__(256, 2) void pv_kernel(const _Float16* probs,
                                                    const _Float16* vT, _Float16* wt) {
    __shared__ alignas(16) _Float16 As[16384];
    __shared__ alignas(16) _Float16 Bs[16384];
    const int m0 = blockIdx.x * 128;
    const int n0 = blockIdx.y * 128;
    const int batch = blockIdx.z;
    const _Float16* A = probs + ((long)batch * 2048 + m0) * 2048;
    const _Float16* B = vT + (long)n0 * 16384 + (long)batch * 2048;
    floatx4 acc[4][4];
    zero_acc(acc);
    gemm_core(A, 2048, B, 16384, 2048, acc, As, Bs);

    const int lane = threadIdx.x & 63;
    const int w = threadIdx.x >> 6;
    const int wr = w >> 1, wc = w & 1;
#pragma unroll
    for (int m = 0; m < 4; ++m) {
#pragma unroll
        for (int n = 0; n < 4; ++n) {
            const int r = wr * 64 + m * 16 + (lane >> 4) * 4;
            const int c = wc * 64 + n * 16 + (lane & 15);
#pragma unroll
            for (int j = 0; j < 4; ++j)
                wt[(long)(batch * 2048 + m0 + r + j) * 1024 + (n0 + c)] =
                    (_Float16)acc[m][n][j];
        }
    }
}

// out = leakyrelu(weighted @ Wf^T + bf), fp32 out.
__global__ __launch_bounds__(256, 2) void out_kernel(const _Float16* wt, const _Float16* Wf,
                                                     const float* bf_, float* out) {
    __shared__ alignas(16) _Float16 As[16384];
    __shared__ alignas(16) _Float16 Bs[16384];
    const int m0 = blockIdx.x * 128;
    const int n0 = blockIdx.y * 128;
    const _Float16* A = wt + (long)m0 * 1024;
    const _Float16* B = Wf + (long)n0 * 1024;
    floatx4 acc[4][4];
    zero_acc(acc);
    gemm_core(A, 1024, B, 1024, 1024, acc, As, Bs);

    const int lane = threadIdx.x & 63;
    const int w = threadIdx.x >> 6;
    const int wr = w >> 1, wc = w & 1;
#pragma unroll
    for (int m = 0; m < 4; ++m) {
#pragma unroll
        for (int n = 0; n < 4; ++n) {
            const int r = wr * 64 + m * 16 + (lane >> 4) * 4;
            const int c = wc * 64 + n * 16 + (lane & 15);
            const float bb = bf_[n0 + c];
#pragma unroll
            for (int j = 0; j < 4; ++j) {
                float y = acc[m][n][j] + bb;
                y = (y >= 0.f) ? y : 0.2f * y;
                out[(long)(m0 + r + j) * 1024 + (n0 + c)] = y;
            }
        }
    }
}

// ---------------- launcher ----------------
extern "C" void kernel_launch(void* const* d_in, const int* in_sizes, int n_in,
                              void* d_out, int out_size, void* d_ws, size_t ws_size,
                              hipStream_t stream) {
    const float* e1 = (const float*)d_in[0];
    const float* e2 = (const float*)d_in[1];
    const float* e3 = (const float*)d_in[2];
    const float* Wq = (const float*)d_in[3];
    const float* bq = (const float*)d_in[4];
    const float* Wk = (const float*)d_in[5];
    const float* bk = (const float*)d_in[6];
    const float* Wv = (const float*)d_in[7];
    const float* bv = (const float*)d_in[8];
    const float* Wf = (const float*)d_in[9];
    const float* bf_ = (const float*)d_in[10];
    float* out = (float*)d_out;

    char* ws = (char*)d_ws;
    const size_t MB = 1024 * 1024;
    _Float16* Xh    = (_Float16*)(ws + 0);        // 32 MiB
    _Float16* Wh    = (_Float16*)(ws + 32 * MB);  // 8 MiB [4][1024][1024]
    _Float16* qh    = (_Float16*)(ws + 40 * MB);  // 32 MiB
    _Float16* kh    = (_Float16*)(ws + 72 * MB);  // 32 MiB
    _Float16* vT    = (_Float16*)(ws + 104 * MB); // 32 MiB [1024][16384]
    _Float16* wt    = (_Float16*)(ws + 136 * MB); // 32 MiB
    _Float16* probs = (_Float16*)(ws + 168 * MB); // 64 MiB [8][2048][2048]
    float* scores   = (float*)(ws + 232 * MB);    // NB * 16 MiB scratch

    long nb_max = ((long)ws_size - 232 * (long)MB) / (16 * (long)MB);
    int NB = (int)(nb_max < 1 ? 1 : (nb_max > 8 ? 8 : nb_max));

    build_x_kernel<<<16384, 256, 0, stream>>>(e1, e2, e3, Xh);
    conv_w_kernel<<<4096, 256, 0, stream>>>(Wq, Wk, Wv, Wf, Wh);
    qkv_kernel<<<dim3(128, 8, 3), 256, 0, stream>>>(Xh, Wh, bq, bk, bv, qh, kh, vT);
    for (int b0 = 0; b0 < 8; b0 += NB) {
        int nb = 8 - b0 < NB ? 8 - b0 : NB;
        scores_kernel<<<dim3(16, 16, nb), 256, 0, stream>>>(qh, kh, scores, b0);
        softmax_kernel<<<dim3(2048, nb), 256, 0, stream>>>(scores, probs, b0);
    }
    pv_kernel<<<dim3(16, 8, 8), 256, 0, stream>>>(probs, vT, wt);
    out_kernel<<<dim3(128, 8), 256, 0, stream>>>(wt, Wh + 3 * 1048576, bf_, out);
}